// Round 7
// baseline (107.954 us; speedup 1.0000x reference)
//
#include <hip/hip_runtime.h>
#include <cstdint>

// ---------------------------------------------------------------------------
// QuantumBranch, R10: decouple compute from streaming stores.
// R3..R9 post-mortem: the main kernel is pinned at ~44-48us across FIVE
// different data paths; R8 counters show VALUBusy 12%, HBM 18%, Occ 20% —
// no pipe loaded. The harness fill proves 5.9TB/s at 8.6% occupancy with a
// pure-store wave structure. R10 makes the store side structurally
// identical to the fill:
//   qb_compute: per-thread circuit -> q,inv; writes 20B into the head of
//               the sample's own out-slot (no LDS/barrier/exchange).
//   qb_expand:  fill-like streamer, 2048 blocks x 8 grid-stride iters;
//               reads the 20B scratch (same wave rewrites that slot ->
//               no cross-wave hazard), 20 FMA, 1 float4 store per iter;
//               all 8 loads hoisted ahead of all stores.
// q/inv round-trip memory as exact f32 bits; expansion FMA sequence is
// R9's store phase verbatim -> absmax stays exactly 0.015625.
// Diagnostic: rocprof now splits the wall between compute and streaming.
//
// Math (verified R1-R9): circuit collapses to V = U*diag((-i)^popc),
// z_w = sum_i +/- (r_i^2+s_i^2), r=Re(V)m, s=Im(V)m, m = product-state
// magnitudes from tanh(x)*pi/2. LayerNorm collapses to a 4x4 quadratic
// form: out[b,k] = inv_b*(A[k].q_b + B0[k]) + beta[k].
// ---------------------------------------------------------------------------

// ws float offsets (global workspace, 856 floats — proven fits since R3)
#define WS_VRT 0     // 256: Re(V)^T  [col*16+row]
#define WS_VIT 256   // 256: Im(V)^T
#define WS_A   512   // 256: (W-colmean)*gamma  [k*4+w]
#define WS_B0  768   // 64:  (b-bmean)*gamma
#define WS_G   832   // 16:  G[4][4]
#define WS_g   848   // 4
#define WS_C0  852   // 1

// One wave, no barriers. lane = row*4 + cg; lane holds U[row][4cg..4cg+3].
__global__ __launch_bounds__(64) void qb_setup(const float* __restrict__ wts,
                                               const float* __restrict__ W,
                                               const float* __restrict__ bias,
                                               const float* __restrict__ gamma,
                                               float* __restrict__ ws) {
    const int lane = threadIdx.x;
    const int row  = lane >> 2;
    const int cg   = lane & 3;

    float ur[4], ui[4];   // U[row][4cg+c]
    #pragma unroll
    for (int c = 0; c < 4; ++c) {
        ur[c] = (row == 4*cg + c) ? 1.f : 0.f;
        ui[c] = 0.f;
    }

    #pragma unroll
    for (int l = 0; l < 2; ++l) {
        #pragma unroll
        for (int w = 0; w < 4; ++w) {
            const float ph = wts[l*12 + w*3 + 0];
            const float th = wts[l*12 + w*3 + 1];
            const float om = wts[l*12 + w*3 + 2];
            float st, ct; __sincosf(0.5f*th, &st, &ct);
            float sp, cp; __sincosf(0.5f*(ph+om), &sp, &cp);
            float sm, cm; __sincosf(0.5f*(ph-om), &sm, &cm);
            const float a00r =  cp*ct, a00i = -sp*ct;
            const float a01r = -cm*st, a01i = -sm*st;
            const float a10r =  cm*st, a10i = -sm*st;
            const float a11r =  cp*ct, a11i =  sp*ct;
            const int m8 = 8 >> w;
            const int xm = m8 << 2;            // lane xor mask for row^m8
            const bool hi = (row & m8) != 0;
            #pragma unroll
            for (int c = 0; c < 4; ++c) {
                const float pr = __shfl_xor(ur[c], xm, 64);
                const float pi = __shfl_xor(ui[c], xm, 64);
                float nr, ni;
                if (!hi) {
                    nr = a00r*ur[c] - a00i*ui[c] + a01r*pr - a01i*pi;
                    ni = a00r*ui[c] + a00i*ur[c] + a01r*pi + a01i*pr;
                } else {
                    nr = a11r*ur[c] - a11i*ui[c] + a10r*pr - a10i*pi;
                    ni = a11r*ui[c] + a11i*ur[c] + a10r*pi + a10i*pr;
                }
                ur[c] = nr; ui[c] = ni;
            }
        }
        const int rr = (l == 0) ? 1 : 2;
        #pragma unroll
        for (int w = 0; w < 4; ++w) {
            const int cmk = 8 >> w;
            const int tmk = 8 >> ((w + rr) & 3);
            const int src = (row & cmk) ? (row ^ tmk) : row;
            const int srcLane = src*4 + cg;
            #pragma unroll
            for (int c = 0; c < 4; ++c) {
                ur[c] = __shfl(ur[c], srcLane, 64);
                ui[c] = __shfl(ui[c], srcLane, 64);
            }
        }
    }

    // V = U * diag((-i)^popc); store transposed: ws[VRT + col*16 + row]
    #pragma unroll
    for (int c = 0; c < 4; ++c) {
        const int col = 4*cg + c;
        const int p = __popc(col) & 3;
        float vr, vi;
        if (p == 0)      { vr =  ur[c]; vi =  ui[c]; }
        else if (p == 1) { vr =  ui[c]; vi = -ur[c]; }
        else if (p == 2) { vr = -ur[c]; vi = -ui[c]; }
        else             { vr = -ui[c]; vi =  ur[c]; }
        ws[WS_VRT + col*16 + row] = vr;
        ws[WS_VIT + col*16 + row] = vi;
    }

    // Projection / layernorm constants: lane k
    {
        const int k = lane;
        float w0 = W[k*4+0], w1 = W[k*4+1], w2 = W[k*4+2], w3 = W[k*4+3];
        float bk = bias[k];
        auto wsum = [](float v) {
            #pragma unroll
            for (int o = 32; o; o >>= 1) v += __shfl_xor(v, o, 64);
            return v;
        };
        const float inv64 = 1.f/64.f;
        const float m0 = wsum(w0)*inv64, m1 = wsum(w1)*inv64;
        const float m2 = wsum(w2)*inv64, m3 = wsum(w3)*inv64;
        const float bm = wsum(bk)*inv64;
        float cc[4] = {w0-m0, w1-m1, w2-m2, w3-m3};
        const float bc = bk - bm;
        const float gk = gamma[k];
        #pragma unroll
        for (int w = 0; w < 4; ++w) ws[WS_A + k*4 + w] = cc[w]*gk;
        ws[WS_B0 + k] = bc*gk;
        #pragma unroll
        for (int a = 0; a < 4; ++a)
            #pragma unroll
            for (int b2 = a; b2 < 4; ++b2) {
                const float s = wsum(cc[a]*cc[b2])*inv64;
                if (k == 0) {
                    ws[WS_G + a*4 + b2] = s;
                    ws[WS_G + b2*4 + a] = s;
                }
            }
        #pragma unroll
        for (int a = 0; a < 4; ++a) {
            const float s = wsum(bc*cc[a])*inv64;
            if (k == 0) ws[WS_g + a] = s;
        }
        {
            const float s = wsum(bc*bc)*inv64;
            if (k == 0) ws[WS_C0] = s;
        }
    }
}

// Per-thread circuit -> q, inv. Pure VALU + uniform SGPR loads of V/G/g/C0.
// Writes 20B scratch into the head of the sample's own 64-float out slot.
__global__ __launch_bounds__(256) void qb_compute(const float* __restrict__ x,
                                                  const float* __restrict__ ws,
                                                  float* __restrict__ out) {
    const int sample = blockIdx.x * 256 + threadIdx.x;
    const float4 xv = ((const float4*)x)[sample];

    // ---- product-state magnitudes m[16] ----
    float m[16];
    {
        const float xa[4] = {xv.x, xv.y, xv.z, xv.w};
        float c4[4], s4[4];
        #pragma unroll
        for (int w = 0; w < 4; ++w) {
            const float h = tanhf(xa[w]) * 1.5707963267948966f;
            __sincosf(h, &s4[w], &c4[w]);
        }
        const float e01[4] = {c4[0]*c4[1], c4[0]*s4[1], s4[0]*c4[1], s4[0]*s4[1]};
        const float e23[4] = {c4[2]*c4[3], c4[2]*s4[3], s4[2]*c4[3], s4[2]*s4[3]};
        #pragma unroll
        for (int j = 0; j < 16; ++j) m[j] = e01[j>>2]*e23[j&3];
    }

    // ---- matvec: V via uniform loads (s_load/SGPR path, R9) ----
    float r[16], si[16];
    #pragma unroll
    for (int i = 0; i < 16; ++i) { r[i] = 0.f; si[i] = 0.f; }
    #pragma unroll
    for (int j = 0; j < 16; ++j) {
        const float mj = m[j];
        #pragma unroll
        for (int i = 0; i < 16; ++i) {
            r[i]  = fmaf(ws[WS_VRT + j*16 + i], mj, r[i]);
            si[i] = fmaf(ws[WS_VIT + j*16 + i], mj, si[i]);
        }
    }

    // ---- finish: z -> softmax -> var -> inv ----
    float z0 = 0.f, z1 = 0.f, z2 = 0.f, z3 = 0.f;
    #pragma unroll
    for (int i = 0; i < 16; ++i) {
        const float p = r[i]*r[i] + si[i]*si[i];
        z0 += (i & 8) ? -p : p;
        z1 += (i & 4) ? -p : p;
        z2 += (i & 2) ? -p : p;
        z3 += (i & 1) ? -p : p;
    }
    const float mx = fmaxf(fmaxf(z0, z1), fmaxf(z2, z3));
    const float e0 = __expf(z0-mx), e1 = __expf(z1-mx);
    const float e2 = __expf(z2-mx), e3 = __expf(z3-mx);
    const float rs = 1.f / (e0+e1+e2+e3);
    const float qx = e0*rs, qy = e1*rs, qz = e2*rs, qw = e3*rs;

    float var = ws[WS_C0];
    {
        const float qa[4] = {qx, qy, qz, qw};
        #pragma unroll
        for (int a = 0; a < 4; ++a) {
            float t = 2.f * ws[WS_g + a];
            #pragma unroll
            for (int b2 = 0; b2 < 4; ++b2) t = fmaf(ws[WS_G + a*4 + b2], qa[b2], t);
            var = fmaf(qa[a], t, var);
        }
    }
    const float inv = rsqrtf(var + 1e-5f);

    // ---- scratch: 20B into the head of this sample's out slot ----
    float* slot = out + (size_t)sample * 64;
    *(float4*)slot = make_float4(qx, qy, qz, qw);
    slot[4] = inv;
}

// Fill-like streamer: 2048 blocks x 256 threads x 8 grid-stride iters cover
// all 4,194,304 output float4s. Reads each sample's 20B scratch (the SAME
// wave rewrites that slot; data dependency orders read-before-write),
// 20 FMA, one float4 store. Loads hoisted ahead of all stores.
__global__ __launch_bounds__(256) void qb_expand(const float* __restrict__ beta,
                                                 const float* __restrict__ ws,
                                                 float* out) {  // NOT restrict: reads scratch from out
    const int tid = threadIdx.x;
    const int kg  = tid & 15;          // k-group, iter-invariant (stride % 16 == 0)

    float4 A4[4];
    #pragma unroll
    for (int u = 0; u < 4; ++u) A4[u] = ((const float4*)(ws + WS_A))[kg*4 + u];
    const float4 B04v = ((const float4*)(ws + WS_B0))[kg];
    const float4 Bt4v = ((const float4*)beta)[kg];
    const float B04[4] = {B04v.x, B04v.y, B04v.z, B04v.w};
    const float Bt4[4] = {Bt4v.x, Bt4v.y, Bt4v.z, Bt4v.w};

    const size_t f0 = (size_t)blockIdx.x * 256 + tid;
    const size_t stride = (size_t)2048 * 256;

    float4 qs[8]; float ivs[8];
    #pragma unroll
    for (int it = 0; it < 8; ++it) {
        const size_t f = f0 + (size_t)it * stride;
        const float* slot = out + (f >> 4) * 64;
        qs[it]  = *(const float4*)slot;
        ivs[it] = slot[4];
    }
    #pragma unroll
    for (int it = 0; it < 8; ++it) {
        const size_t f = f0 + (size_t)it * stride;
        const float4 q  = qs[it];
        const float  iv = ivs[it];
        float4 o;
        float* op = (float*)&o;
        #pragma unroll
        for (int u = 0; u < 4; ++u) {
            float t = B04[u];
            t = fmaf(A4[u].x, q.x, t);
            t = fmaf(A4[u].y, q.y, t);
            t = fmaf(A4[u].z, q.z, t);
            t = fmaf(A4[u].w, q.w, t);
            op[u] = fmaf(t, iv, Bt4[u]);
        }
        ((float4*)out)[f] = o;
    }
}

extern "C" void kernel_launch(void* const* d_in, const int* in_sizes, int n_in,
                              void* d_out, int out_size, void* d_ws, size_t ws_size,
                              hipStream_t stream) {
    const float* x     = (const float*)d_in[0];
    const float* wts   = (const float*)d_in[1];
    const float* W     = (const float*)d_in[2];
    const float* bias  = (const float*)d_in[3];
    const float* gamma = (const float*)d_in[4];
    const float* beta  = (const float*)d_in[5];
    float* out = (float*)d_out;
    float* ws  = (float*)d_ws;
    const int B = in_sizes[0] / 4;   // 262144

    hipLaunchKernelGGL(qb_setup,   dim3(1),       dim3(64),  0, stream, wts, W, bias, gamma, ws);
    hipLaunchKernelGGL(qb_compute, dim3(B / 256), dim3(256), 0, stream, x, ws, out);
    hipLaunchKernelGGL(qb_expand,  dim3(2048),    dim3(256), 0, stream, beta, ws, out);
}